// Round 7
// baseline (590.891 us; speedup 1.0000x reference)
//
#include <hip/hip_runtime.h>
#include <stdint.h>

// GraphAttentionLayer kernel set for MI355X (gfx950). Round 7.
// Pipeline:
//   K1 conv_wt : W[k][c] fp32 -> WT[c][k] bf16 (LDS-tiled transpose)
//   K2 wh_gemm : Wh = h@W + bW via bf16 MFMA -> WhT[c][i] bf16
//                + fused epilogue: raw scores s1 = Wh@a1, s2 = Wh@a2
//   K3 adj2b   : adj int32 (268 MB) -> tiled 1-bit mask bmT (8 MB).
//                bmT[i][p][it]: byte (p,it) of row i = adjacency bits of
//                cols it*128 + p*8 .. +8. HBM-streaming, ~45 us.
//   K4 attn3   : fused masked-softmax @ Wh, 32 rows x 256 cols/block.
//                w computed in registers from bitmask byte (L2-resident,
//                +1-iter prefetch) + s2; -> LDS A operand; B = WhT tile via
//                global_load_lds(16B). R6 lesson: adj HBM loads were
//                re-serialized at every barrier (vmcnt(0) drain, ~900cy);
//                bitmask removes both that latency and ~200 MB of fetch.

#define NN 8192
#define DD 512

typedef __attribute__((ext_vector_type(8))) short short8;
typedef __attribute__((ext_vector_type(4))) float f32x4;
typedef __attribute__((ext_vector_type(4))) float float4v;
typedef __attribute__((ext_vector_type(4))) unsigned short ushort4v;

__device__ __forceinline__ uint16_t f2bf(float f) {
  union { float f; uint32_t u; } v; v.f = f;
  uint32_t u = v.u;
  u += 0x7fffu + ((u >> 16) & 1u);   // round-nearest-even
  return (uint16_t)(u >> 16);
}

__device__ __forceinline__ void async_copy16(uint16_t* lds, const uint16_t* g) {
  __builtin_amdgcn_global_load_lds(
      (const __attribute__((address_space(1))) uint32_t*)g,
      (__attribute__((address_space(3))) uint32_t*)lds, 16, 0, 0);
}

// ---- K1: tiled transpose+convert W (512x512) ----
__global__ __launch_bounds__(256) void conv_wt(const float* __restrict__ W,
                                               uint16_t* __restrict__ WT) {
  __shared__ float ts[64][65];
  int tid = threadIdx.x;
  int kt = (blockIdx.x >> 3) * 64, ct = (blockIdx.x & 7) * 64;
  #pragma unroll
  for (int it = 0; it < 4; ++it) {
    int idx = it * 256 + tid;
    int r = idx >> 4, q = idx & 15;
    float4v v = *(const float4v*)(W + (size_t)(kt + r) * 512 + ct + q * 4);
    ts[r][q * 4 + 0] = v.x; ts[r][q * 4 + 1] = v.y;
    ts[r][q * 4 + 2] = v.z; ts[r][q * 4 + 3] = v.w;
  }
  __syncthreads();
  #pragma unroll
  for (int it = 0; it < 4; ++it) {
    int idx = it * 256 + tid;
    int c = idx >> 4, q = idx & 15;
    ushort4v p;
    p.x = f2bf(ts[q * 4 + 0][c]); p.y = f2bf(ts[q * 4 + 1][c]);
    p.z = f2bf(ts[q * 4 + 2][c]); p.w = f2bf(ts[q * 4 + 3][c]);
    *(ushort4v*)(WT + (size_t)(ct + c) * 512 + kt + q * 4) = p;
  }
}

// ---- K2: Wh GEMM -> WhT[c][i] bf16, fused raw scores s1,s2 ----
__global__ __launch_bounds__(512) void wh_gemm(const float* __restrict__ h,
                                               const uint16_t* __restrict__ WT,
                                               const float* __restrict__ bW,
                                               const float* __restrict__ a1,
                                               const float* __restrict__ a2,
                                               uint16_t* __restrict__ WhT,
                                               float* __restrict__ s1g,
                                               float* __restrict__ s2g) {
  __shared__ __align__(16) uint16_t At[32 * 32];
  __shared__ __align__(16) uint16_t Bt[512 * 32];
  __shared__ float s1loc[32], s2loc[32];
  int tid = threadIdx.x;
  int wave = tid >> 6, lane = tid & 63;
  int l15 = lane & 15, quad = lane >> 4;
  int i0 = blockIdx.x * 32;
  if (tid < 32) { s1loc[tid] = 0.f; s2loc[tid] = 0.f; }
  f32x4 acc[2][4] = {};
  for (int k0 = 0; k0 < 512; k0 += 32) {
    if (tid < 256) {
      int r = tid >> 3, ks = (tid & 7) * 4;
      float4v hv = *(const float4v*)(h + (size_t)(i0 + r) * 512 + k0 + ks);
      ushort4v p;
      p.x = f2bf(hv.x); p.y = f2bf(hv.y); p.z = f2bf(hv.z); p.w = f2bf(hv.w);
      *(ushort4v*)&At[r * 32 + ks] = p;
    }
    #pragma unroll
    for (int rr = 0; rr < 4; ++rr) {
      int idx = rr * 512 + tid;
      int c = idx >> 2, q = idx & 3;
      async_copy16(&Bt[idx * 8], WT + c * 512 + k0 + q * 8);
    }
    __syncthreads();
    short8 a0 = *(const short8*)&At[l15 * 32 + quad * 8];
    short8 a1f = *(const short8*)&At[(l15 + 16) * 32 + quad * 8];
    #pragma unroll
    for (int nt = 0; nt < 4; ++nt) {
      int c = wave * 64 + nt * 16 + l15;
      short8 b = *(const short8*)&Bt[c * 32 + quad * 8];
      acc[0][nt] = __builtin_amdgcn_mfma_f32_16x16x32_bf16(a0, b, acc[0][nt], 0, 0, 0);
      acc[1][nt] = __builtin_amdgcn_mfma_f32_16x16x32_bf16(a1f, b, acc[1][nt], 0, 0, 0);
    }
    __syncthreads();
  }
  #pragma unroll
  for (int mt = 0; mt < 2; ++mt) {
    int ib = i0 + mt * 16 + quad * 4;
    float r1[4] = {0.f, 0.f, 0.f, 0.f};
    float r2[4] = {0.f, 0.f, 0.f, 0.f};
    #pragma unroll
    for (int nt = 0; nt < 4; ++nt) {
      int c = wave * 64 + nt * 16 + l15;
      float bias = bW[c];
      float a1c = a1[c], a2c = a2[c];
      float v0 = acc[mt][nt].x + bias;
      float v1 = acc[mt][nt].y + bias;
      float v2 = acc[mt][nt].z + bias;
      float v3 = acc[mt][nt].w + bias;
      ushort4v p;
      p.x = f2bf(v0); p.y = f2bf(v1); p.z = f2bf(v2); p.w = f2bf(v3);
      *(ushort4v*)&WhT[(size_t)c * 8192 + ib] = p;
      r1[0] = fmaf(v0, a1c, r1[0]); r1[1] = fmaf(v1, a1c, r1[1]);
      r1[2] = fmaf(v2, a1c, r1[2]); r1[3] = fmaf(v3, a1c, r1[3]);
      r2[0] = fmaf(v0, a2c, r2[0]); r2[1] = fmaf(v1, a2c, r2[1]);
      r2[2] = fmaf(v2, a2c, r2[2]); r2[3] = fmaf(v3, a2c, r2[3]);
    }
    #pragma unroll
    for (int v = 0; v < 4; ++v) {
      int row = mt * 16 + quad * 4 + v;
      atomicAdd(&s1loc[row], r1[v]);
      atomicAdd(&s2loc[row], r2[v]);
    }
  }
  __syncthreads();
  if (tid < 32) {
    s1g[i0 + tid] = s1loc[tid];
    s2g[i0 + tid] = s2loc[tid];
  }
}

// ---- K3: adj -> tiled bitmask. One row per block, 256 thr x 32 cols. ----
// Byte (p,it) of row i (addr i*1024 + p*64 + it) holds bits of cols
// it*128 + p*8 .. +8 (bit u = col offset u).
__global__ __launch_bounds__(256) void adj2b(const int* __restrict__ adj,
                                             uint8_t* __restrict__ bmT) {
  int i = blockIdx.x;
  int t = threadIdx.x;                    // covers cols 32t .. 32t+31
  const int* ap = adj + (size_t)i * 8192 + t * 32;
  uint32_t bits = 0;
  #pragma unroll
  for (int q4 = 0; q4 < 8; ++q4) {
    int4 v = *(const int4*)(ap + q4 * 4);
    bits |= (v.x > 0 ? 1u : 0u) << (q4 * 4 + 0);
    bits |= (v.y > 0 ? 1u : 0u) << (q4 * 4 + 1);
    bits |= (v.z > 0 ? 1u : 0u) << (q4 * 4 + 2);
    bits |= (v.w > 0 ? 1u : 0u) << (q4 * 4 + 3);
  }
  size_t base = (size_t)i * 1024 + (size_t)(t >> 2);
  int p0 = 4 * (t & 3);
  bmT[base + (size_t)(p0 + 0) * 64] = (uint8_t)(bits & 0xff);
  bmT[base + (size_t)(p0 + 1) * 64] = (uint8_t)((bits >> 8) & 0xff);
  bmT[base + (size_t)(p0 + 2) * 64] = (uint8_t)((bits >> 16) & 0xff);
  bmT[base + (size_t)(p0 + 3) * 64] = (uint8_t)((bits >> 24) & 0xff);
}

// ---- K4: fused masked-softmax attention @ Wh ----
// Block = 32 out-rows x 256 out-cols. 512 thr = 8 waves.
// Block map: cb=(x>>2)&1, rb=((x>>3)<<2)|(x&3) -> fixed cb occupies fixed
// XCDs (x%8 in {4cb..4cb+3}); each XCD L2 (4 MiB) holds exactly its 4 MB
// WhT half -> B staging is an L2 hit after first pass.
// LDS: Bt 64KB + At 8KB + dred 2KB -> 2 blocks/CU.
__global__ __launch_bounds__(512, 4) void attn3(const uint8_t* __restrict__ bmT,
                                                const float* __restrict__ s1,
                                                const float* __restrict__ s2,
                                                const float* __restrict__ b1,
                                                const float* __restrict__ b2,
                                                const uint16_t* __restrict__ WhT,
                                                float* __restrict__ out) {
  __shared__ __align__(16) uint16_t At[32 * 128];    // 8 KB, XOR-16 swizzled
  __shared__ __align__(16) uint16_t Bt[256 * 128];   // 64 KB, XOR-16 swizzled
  __shared__ float dred[512];
  __shared__ float dloc[32];
  int tid = threadIdx.x;
  int wave = tid >> 6, lane = tid & 63;
  int l15 = lane & 15, quad = lane >> 4;
  int x = blockIdx.x;
  int cb = (x >> 2) & 1;
  int rb = ((x >> 3) << 2) | (x & 3);
  int i0 = rb * 32, c0 = cb * 256;
  // w-generation role: row wr (0..31), chunk p (0..15) of 8 cols
  int wr = tid >> 4, p = tid & 15;
  float s1v = s1[i0 + wr] + b1[0] + b2[0];
  const uint8_t* bmp = bmT + (size_t)(i0 + wr) * 1024 + p * 64;
  const float* s2p = s2 + p * 8;
  uint16_t* awp = &At[wr * 128 + ((p ^ (wr & 15)) * 8)];
  float dpart = 0.f;
  f32x4 acc[2][2] = {};
  uint32_t bcur = bmp[0];
  for (int it = 0; it < 64; ++it) {
    int j0 = it * 128;
    // B staging: 256 rows x 128 j = 64 KB = 4096 chunks, 8/thread
    #pragma unroll
    for (int s = 0; s < 8; ++s) {
      int idx = s * 512 + tid;
      int r = idx >> 4, pp = idx & 15;
      int sc = pp ^ (r & 15);
      async_copy16(&Bt[idx * 8], WhT + (size_t)(c0 + r) * 8192 + j0 + sc * 8);
    }
    uint32_t bnext = bmp[(it + 1) & 63];   // L2-hot byte, +1-iter prefetch
    float4v sv0 = *(const float4v*)(s2p + j0);
    float4v sv1 = *(const float4v*)(s2p + j0 + 4);
    // compute my 8 w values (cols j0 + p*8 + 0..7)
    float e, wf[8];
    e = s1v + sv0.x; e = fmaxf(e, 0.2f * e); wf[0] = (bcur & 1u)   ? __expf(e) : 0.f;
    e = s1v + sv0.y; e = fmaxf(e, 0.2f * e); wf[1] = (bcur & 2u)   ? __expf(e) : 0.f;
    e = s1v + sv0.z; e = fmaxf(e, 0.2f * e); wf[2] = (bcur & 4u)   ? __expf(e) : 0.f;
    e = s1v + sv0.w; e = fmaxf(e, 0.2f * e); wf[3] = (bcur & 8u)   ? __expf(e) : 0.f;
    e = s1v + sv1.x; e = fmaxf(e, 0.2f * e); wf[4] = (bcur & 16u)  ? __expf(e) : 0.f;
    e = s1v + sv1.y; e = fmaxf(e, 0.2f * e); wf[5] = (bcur & 32u)  ? __expf(e) : 0.f;
    e = s1v + sv1.z; e = fmaxf(e, 0.2f * e); wf[6] = (bcur & 64u)  ? __expf(e) : 0.f;
    e = s1v + sv1.w; e = fmaxf(e, 0.2f * e); wf[7] = (bcur & 128u) ? __expf(e) : 0.f;
    dpart += ((wf[0] + wf[1]) + (wf[2] + wf[3])) + ((wf[4] + wf[5]) + (wf[6] + wf[7]));
    short8 pk;
    pk[0] = (short)f2bf(wf[0]); pk[1] = (short)f2bf(wf[1]);
    pk[2] = (short)f2bf(wf[2]); pk[3] = (short)f2bf(wf[3]);
    pk[4] = (short)f2bf(wf[4]); pk[5] = (short)f2bf(wf[5]);
    pk[6] = (short)f2bf(wf[6]); pk[7] = (short)f2bf(wf[7]);
    *(short8*)awp = pk;            // ds_write_b128
    bcur = bnext;
    __syncthreads();               // drains async B + A ds_writes (L2-fast now)
    // MFMA: 4 k-chunks x (2m x 2n) = 16 per wave
    int brow0 = wave * 32 + l15;
    int brow1 = brow0 + 16;
    #pragma unroll
    for (int ks = 0; ks < 4; ++ks) {
      int ch = ks * 4 + quad;
      short8 b0 = *(const short8*)&Bt[brow0 * 128 + ((ch ^ l15) * 8)];
      short8 b1f = *(const short8*)&Bt[brow1 * 128 + ((ch ^ l15) * 8)];
      short8 am0 = *(const short8*)&At[l15 * 128 + ((ch ^ l15) * 8)];
      short8 am1 = *(const short8*)&At[(l15 + 16) * 128 + ((ch ^ l15) * 8)];
      acc[0][0] = __builtin_amdgcn_mfma_f32_16x16x32_bf16(am0, b0, acc[0][0], 0, 0, 0);
      acc[0][1] = __builtin_amdgcn_mfma_f32_16x16x32_bf16(am0, b1f, acc[0][1], 0, 0, 0);
      acc[1][0] = __builtin_amdgcn_mfma_f32_16x16x32_bf16(am1, b0, acc[1][0], 0, 0, 0);
      acc[1][1] = __builtin_amdgcn_mfma_f32_16x16x32_bf16(am1, b1f, acc[1][1], 0, 0, 0);
    }
    __syncthreads();
  }
  // denominator reduce: 16 partials per row
  dred[tid] = dpart;
  __syncthreads();
  if (tid < 32) {
    float s = 0.f;
    #pragma unroll
    for (int q = 0; q < 16; ++q) s += dred[tid * 16 + q];
    dloc[tid] = 1.0f / s;
  }
  __syncthreads();
  // epilogue
  #pragma unroll
  for (int mt = 0; mt < 2; ++mt) {
    #pragma unroll
    for (int nt = 0; nt < 2; ++nt) {
      int c = c0 + wave * 32 + nt * 16 + l15;
      #pragma unroll
      for (int v = 0; v < 4; ++v) {
        int row = mt * 16 + quad * 4 + v;
        out[(size_t)(i0 + row) * 512 + c] = acc[mt][nt][v] * dloc[row];
      }
    }
  }
}

extern "C" void kernel_launch(void* const* d_in, const int* in_sizes, int n_in,
                              void* d_out, int out_size, void* d_ws, size_t ws_size,
                              hipStream_t stream) {
  const float* h   = (const float*)d_in[0];
  const int*   adj = (const int*)d_in[1];
  const float* W   = (const float*)d_in[2];
  const float* bW  = (const float*)d_in[3];
  const float* a1  = (const float*)d_in[4];
  const float* b1  = (const float*)d_in[5];
  const float* a2  = (const float*)d_in[6];
  const float* b2  = (const float*)d_in[7];
  float* out = (float*)d_out;
  char* ws = (char*)d_ws;

  uint16_t* WhT = (uint16_t*)(ws);               // 8388608 B
  uint16_t* WT  = (uint16_t*)(ws + 8388608);     // 524288 B
  float* s1     = (float*)(ws + 8912896);        // 32768 B
  float* s2     = (float*)(ws + 8945664);        // 32768 B
  uint8_t* bmT  = (uint8_t*)(ws + 8978432);      // 8388608 B (tot ~17.4 MB)

  conv_wt<<<64, 256, 0, stream>>>(W, WT);
  wh_gemm<<<256, 512, 0, stream>>>(h, WT, bW, a1, a2, WhT, s1, s2);
  adj2b<<<8192, 256, 0, stream>>>(adj, bmT);
  attn3<<<512, 512, 0, stream>>>(bmT, s1, s2, b1, b2, WhT, out);
}